// Round 21
// baseline (176.232 us; speedup 1.0000x reference)
//
#include <hip/hip_runtime.h>
#include <hip/hip_bf16.h>

#define N_NODES 100000
#define E_EDGES 1600000
#define DIN 256
#define C_OUT 64
#define NID_CNT 10000
#define NEG 0.2f
#define NBUCK 391        // ceil(N_NODES/256) coarse buckets (dst >> 8)
#define CAP 4608         // fixed edges-capacity per bucket
#define GEMM_BLOCKS 391  // ceil(100000/256)
#define BIN_BLOCKS 121   // 391 + 121 = 512 = 2 blocks/CU * 256 CU (all co-resident)
#define BIN_EPB 13224    // ceil(E_EDGES/121)
#define BIN_ITERS 26     // ceil(13224/512)

typedef short bf16x8 __attribute__((ext_vector_type(8)));
typedef float f32x4  __attribute__((ext_vector_type(4)));

__device__ __forceinline__ float lrelu(float x) { return x > 0.f ? x : NEG * x; }
__device__ __forceinline__ unsigned short f2bs(float f) {
    __hip_bfloat16 b = __float2bfloat16(f);
    return *reinterpret_cast<unsigned short*>(&b);
}
__device__ __forceinline__ bf16x8 pack8(float4 a, float4 b) {
    bf16x8 r;
    r[0] = (short)f2bs(a.x); r[1] = (short)f2bs(a.y);
    r[2] = (short)f2bs(a.z); r[3] = (short)f2bs(a.w);
    r[4] = (short)f2bs(b.x); r[5] = (short)f2bs(b.y);
    r[6] = (short)f2bs(b.z); r[7] = (short)f2bs(b.w);
    return r;
}
__device__ __forceinline__ float2 unpk2(unsigned u) {
    return make_float2(__uint_as_float(u << 16), __uint_as_float(u & 0xffff0000u));
}

// ---------------- zero/init scratch ----------------
__global__ __launch_bounds__(256) void k_zero(float* __restrict__ cnt,
                                              int* __restrict__ bkcur) {
    const int t = blockIdx.x * 256 + threadIdx.x;
    if (t < N_NODES) cnt[t] = 0.f;
    if (t < NBUCK) bkcur[t] = t * CAP;   // fixed-capacity bucket bases
}

// ---------------- prep: W/Wid cvt+transpose | id multiplicity ----------------
__global__ __launch_bounds__(256) void k_prep(const float* __restrict__ W,
                                              const float* __restrict__ Wid,
                                              unsigned short* __restrict__ WtG,
                                              unsigned short* __restrict__ WidtG,
                                              const int* __restrict__ nid,
                                              float* __restrict__ cnt) {
    const int b = blockIdx.x;
    const int tid = threadIdx.x;
    if (b < 128) {                       // cvt: 32768 elements
        const int t = b * 256 + tid;
        const int mat = t >> 14;
        const int r = t & 16383;
        const int k = r >> 6, c = r & 63;
        if (mat == 0) WtG[c * DIN + k] = f2bs(W[(long)k * C_OUT + c]);
        else          WidtG[c * DIN + k] = f2bs(Wid[(long)k * C_OUT + c]);
    } else {                             // cnt: 10000 ids
        const int t = (b - 128) * 256 + tid;
        if (t < NID_CNT) atomicAdd(&cnt[nid[t]], 1.0f);
    }
}

// ---------------- mega kernel: gemm blocks (0..390) || bin blocks (391..511) ----------------
__global__ __launch_bounds__(512, 4) void k_mega(const float* __restrict__ x,
                                                 const unsigned short* __restrict__ WtG,
                                                 const unsigned short* __restrict__ WidtG,
                                                 const float* __restrict__ cnt,
                                                 const float* __restrict__ att,
                                                 __hip_bfloat16* __restrict__ hb,
                                                 float* __restrict__ ad,
                                                 float* __restrict__ as,
                                                 const int* __restrict__ ei,
                                                 int* __restrict__ bkcur,
                                                 int2* __restrict__ binned) {
    __shared__ __align__(16) char smem[66560];
    const int blk = blockIdx.x;
    const int tid = threadIdx.x;

    if (blk < GEMM_BLOCKS) {
        char* wlds = smem;                          // 64 KB: wt | wid (swizzled)
        float* cnt_lds = (float*)(smem + 65536);    // 1 KB
        const int w = tid >> 6, l = tid & 63;
        const int g = l >> 4, cl = l & 15;
        const int r0 = blk * 256;

        #pragma unroll
        for (int i = 0; i < 4; ++i) {
            int f = tid + i * 512;     // 2048 chunks of 16B
            int c = f >> 5, s = f & 31;
            int byte = c * 512 + ((s ^ (c & 7)) << 4);
            *(bf16x8*)(wlds + byte)         = *(const bf16x8*)(WtG + (long)c * DIN + s * 8);
            *(bf16x8*)(wlds + 32768 + byte) = *(const bf16x8*)(WidtG + (long)c * DIN + s * 8);
        }
        if (tid < 256) cnt_lds[tid] = (r0 + tid < N_NODES) ? cnt[r0 + tid] : 0.f;
        __syncthreads();

        f32x4 acc1[2][4] = {};
        f32x4 acc2[2][4] = {};

        const int row0 = r0 + w * 32 + cl;
        const float* xp0 = x + (long)min(row0, N_NODES - 1) * DIN + g * 8;
        const float* xp1 = x + (long)min(row0 + 16, N_NODES - 1) * DIN + g * 8;

        float4 xb[2][4];
        xb[0][0] = *(const float4*)(xp0);
        xb[0][1] = *(const float4*)(xp0 + 4);
        xb[0][2] = *(const float4*)(xp1);
        xb[0][3] = *(const float4*)(xp1 + 4);
        #pragma unroll
        for (int kt = 0; kt < 8; ++kt) {
            if (kt < 7) {
                const int nb = (kt + 1) & 1;
                xb[nb][0] = *(const float4*)(xp0 + (kt + 1) * 32);
                xb[nb][1] = *(const float4*)(xp0 + (kt + 1) * 32 + 4);
                xb[nb][2] = *(const float4*)(xp1 + (kt + 1) * 32);
                xb[nb][3] = *(const float4*)(xp1 + (kt + 1) * 32 + 4);
            }
            const int cb = kt & 1;
            bf16x8 a0 = pack8(xb[cb][0], xb[cb][1]);
            bf16x8 a1 = pack8(xb[cb][2], xb[cb][3]);
            #pragma unroll
            for (int ct = 0; ct < 4; ++ct) {
                int c = ct * 16 + cl;
                int byte = c * 512 + (((kt * 4 + g) ^ (c & 7)) << 4);
                bf16x8 bw = *(const bf16x8*)(wlds + byte);
                bf16x8 bi = *(const bf16x8*)(wlds + 32768 + byte);
                acc1[0][ct] = __builtin_amdgcn_mfma_f32_16x16x32_bf16(a0, bw, acc1[0][ct], 0, 0, 0);
                acc1[1][ct] = __builtin_amdgcn_mfma_f32_16x16x32_bf16(a1, bw, acc1[1][ct], 0, 0, 0);
                acc2[0][ct] = __builtin_amdgcn_mfma_f32_16x16x32_bf16(a0, bi, acc2[0][ct], 0, 0, 0);
                acc2[1][ct] = __builtin_amdgcn_mfma_f32_16x16x32_bf16(a1, bi, acc2[1][ct], 0, 0, 0);
            }
        }
        __syncthreads();

        float attv1[4], attv2[4];
        #pragma unroll
        for (int ct = 0; ct < 4; ++ct) {
            attv1[ct] = att[ct * 16 + cl];
            attv2[ct] = att[C_OUT + ct * 16 + cl];
        }
        unsigned short* hbt = (unsigned short*)wlds;  // tile stride 72 elems (144 B)
        #pragma unroll
        for (int rt = 0; rt < 2; ++rt) {
            #pragma unroll
            for (int reg = 0; reg < 4; ++reg) {
                const int rbl = w * 32 + rt * 16 + g * 4 + reg;
                const float cv = cnt_lds[rbl];
                float pd = 0.f, ps = 0.f;
                #pragma unroll
                for (int ct = 0; ct < 4; ++ct) {
                    float hv = acc1[rt][ct][reg] + cv * acc2[rt][ct][reg];
                    pd += hv * attv1[ct];
                    ps += hv * attv2[ct];
                    hbt[rbl * 72 + ct * 16 + cl] = f2bs(hv);
                }
                #pragma unroll
                for (int o = 1; o < 16; o <<= 1) {
                    pd += __shfl_xor(pd, o, 64);
                    ps += __shfl_xor(ps, o, 64);
                }
                if (cl == 0) {
                    int grow = r0 + rbl;
                    if (grow < N_NODES) { ad[grow] = pd; as[grow] = ps; }
                }
            }
        }
        __syncthreads();
        #pragma unroll
        for (int i = 0; i < 4; ++i) {
            int f = tid + i * 512;
            int row = f >> 3, s = f & 7;
            int grow = r0 + row;
            if (grow < N_NODES) {
                bf16x8 v = *(const bf16x8*)(wlds + row * 144 + s * 16);
                *(bf16x8*)((unsigned short*)hb + (long)grow * C_OUT + s * 8) = v;
            }
        }
    } else {
        // ---- bin role: register-staged two-phase scatter into bucket regions ----
        int* cnt_s = (int*)smem;         // NBUCK
        int* base  = cnt_s + NBUCK;      // NBUCK
        int* lcur  = base + NBUCK;       // NBUCK
        const int b2 = blk - GEMM_BLOCKS;
        const int e0 = b2 * BIN_EPB;
        const int e1 = min(e0 + BIN_EPB, E_EDGES);
        for (int i = tid; i < NBUCK; i += 512) cnt_s[i] = 0;
        __syncthreads();
        int se[BIN_ITERS], de[BIN_ITERS];
        #pragma unroll
        for (int j = 0; j < BIN_ITERS; ++j) {
            int e = e0 + j * 512 + tid;
            if (e < e1) {
                se[j] = ei[e];
                de[j] = ei[E_EDGES + e];
                atomicAdd(&cnt_s[de[j] >> 8], 1);
            } else de[j] = -1;
        }
        __syncthreads();
        for (int i = tid; i < NBUCK; i += 512) {
            base[i] = cnt_s[i] ? atomicAdd(&bkcur[i], cnt_s[i]) : 0;
            lcur[i] = 0;
        }
        __syncthreads();
        #pragma unroll
        for (int j = 0; j < BIN_ITERS; ++j) {
            if (de[j] >= 0) {
                int bb = de[j] >> 8;
                int r = atomicAdd(&lcur[bb], 1);
                // nt store of 8B payload: pack (src,dst) into a long long
                long long pv = ((long long)de[j] << 32) | (unsigned)se[j];
                __builtin_nontemporal_store(pv, (long long*)&binned[base[bb] + r]);
            }
        }
    }
}

// ---------------- place: one block per bucket -> fixed-capacity csr + cur ----------------
// 512 threads; scan section guarded to tid<256 with uniform barriers.
// binned entry layout: .x = src (low 32), .y = dst (high 32).
__global__ __launch_bounds__(512) void k_place(const int2* __restrict__ binned,
                                               const int* __restrict__ bkcur,
                                               int* __restrict__ csr,
                                               int* __restrict__ cur) {
    __shared__ int ncnt[256];
    __shared__ int tmp[256];
    __shared__ int ncur[256];
    const int tid = threadIdx.x;
    const int b = blockIdx.x;
    const int lo = b * CAP;
    const int n = bkcur[b] - lo;       // bucket edge count
    const int node0 = b << 8;
    if (tid < 256) ncnt[tid] = 0;
    __syncthreads();
    for (int e = tid; e < n; e += 512)
        atomicAdd(&ncnt[binned[lo + e].y - node0], 1);
    __syncthreads();
    const int v = (tid < 256) ? ncnt[tid] : 0;
    if (tid < 256) tmp[tid] = v;
    __syncthreads();
    for (int o = 1; o < 256; o <<= 1) {
        int t = (tid >= o && tid < 256) ? tmp[tid - o] : 0;
        __syncthreads();
        if (tid < 256) tmp[tid] += t;
        __syncthreads();
    }
    if (tid < 256) {
        const int incl = tmp[tid];
        if (node0 + tid < N_NODES) cur[node0 + tid] = lo + incl;  // global inclusive end
        ncur[tid] = incl - v;  // local exclusive start
    }
    __syncthreads();
    for (int e = tid; e < n; e += 512) {
        int2 p = binned[lo + e];
        int r = atomicAdd(&ncur[p.y - node0], 1);
        __builtin_nontemporal_store(p.x, &csr[lo + r]);
    }
}

// ---------------- gather: 2 nodes/wave (32-lane groups), 2 channels/lane (bf16x2) ----------------
__global__ __launch_bounds__(256) void k_gather(const int* __restrict__ cur,
                                                const int* __restrict__ csr,
                                                const unsigned* __restrict__ hb2,
                                                const float* __restrict__ ad,
                                                const float* __restrict__ as,
                                                float* __restrict__ out) {
    const int lane = threadIdx.x & 63;
    const int lg = lane & 31;                  // lane in group
    const int gb = lane & 32;                  // group broadcast base
    const int i = blockIdx.x * 8 + ((threadIdx.x >> 6) << 1) + (lane >> 5);
    if (i >= N_NODES) return;
    const int end   = cur[i];
    const int start = (i & 255) ? cur[i - 1] : (i >> 8) * CAP;  // fixed-cap bucket base
    const int deg   = end - start;
    const float adi = ad[i];
    const float asi = as[i];
    float2 acc;
    float den;
    if (deg <= 32) {
        int s = 0; float a = -1e30f;
        if (lg < deg) { s = csr[start + lg]; a = as[s]; }
        float mx = fmaxf(a, asi);
        #pragma unroll
        for (int o = 16; o > 0; o >>= 1) mx = fmaxf(mx, __shfl_xor(mx, o, 64));
        const float m = lrelu(adi + mx);
        float w = (lg < deg) ? __expf(lrelu(adi + a) - m) : 0.f;
        const float wself = __expf(lrelu(adi + asi) - m);
        float wsum = w;
        #pragma unroll
        for (int o = 16; o > 0; o >>= 1) wsum += __shfl_xor(wsum, o, 64);
        den = wself + wsum;
        float2 hv = unpk2(hb2[(long)i * 32 + lg]);
        acc = make_float2(wself * hv.x, wself * hv.y);
        int j = 0;
        for (; j + 4 <= deg; j += 4) {
            int   s0 = __shfl(s, gb + j, 64),     s1 = __shfl(s, gb + j + 1, 64),
                  s2 = __shfl(s, gb + j + 2, 64), s3 = __shfl(s, gb + j + 3, 64);
            float w0 = __shfl(w, gb + j, 64),     w1 = __shfl(w, gb + j + 1, 64),
                  w2 = __shfl(w, gb + j + 2, 64), w3 = __shfl(w, gb + j + 3, 64);
            float2 h0 = unpk2(hb2[(long)s0 * 32 + lg]);
            float2 h1 = unpk2(hb2[(long)s1 * 32 + lg]);
            float2 h2 = unpk2(hb2[(long)s2 * 32 + lg]);
            float2 h3 = unpk2(hb2[(long)s3 * 32 + lg]);
            acc.x += w0 * h0.x; acc.y += w0 * h0.y;
            acc.x += w1 * h1.x; acc.y += w1 * h1.y;
            acc.x += w2 * h2.x; acc.y += w2 * h2.y;
            acc.x += w3 * h3.x; acc.y += w3 * h3.y;
        }
        for (; j < deg; ++j) {
            int   sj = __shfl(s, gb + j, 64);
            float wj = __shfl(w, gb + j, 64);
            float2 hj = unpk2(hb2[(long)sj * 32 + lg]);
            acc.x += wj * hj.x; acc.y += wj * hj.y;
        }
    } else {  // rare: deg > 32
        float mx = asi;
        for (int b = 0; b < deg; b += 32) {
            int idx = b + lg;
            if (idx < deg) mx = fmaxf(mx, as[csr[start + idx]]);
        }
        #pragma unroll
        for (int o = 16; o > 0; o >>= 1) mx = fmaxf(mx, __shfl_xor(mx, o, 64));
        const float m = lrelu(adi + mx);
        const float wself = __expf(lrelu(adi + asi) - m);
        float2 hv = unpk2(hb2[(long)i * 32 + lg]);
        acc = make_float2(wself * hv.x, wself * hv.y);
        den = wself;
        for (int b = 0; b < deg; b += 32) {
            int idx = b + lg;
            int s = 0; float w = 0.f;
            if (idx < deg) {
                s = csr[start + idx];
                w = __expf(lrelu(adi + as[s]) - m);
            }
            const int cnt2 = min(32, deg - b);
            for (int j = 0; j < cnt2; ++j) {
                int   sj = __shfl(s, gb + j, 64);
                float wj = __shfl(w, gb + j, 64);
                float2 hj = unpk2(hb2[(long)sj * 32 + lg]);
                acc.x += wj * hj.x; acc.y += wj * hj.y;
            }
            float wsum = w;
            #pragma unroll
            for (int o = 16; o > 0; o >>= 1) wsum += __shfl_xor(wsum, o, 64);
            den += wsum;
        }
    }
    const float r = 1.f / (den + 1e-16f);
    *(float2*)(out + (long)i * C_OUT + lg * 2) = make_float2(acc.x * r, acc.y * r);
}

extern "C" void kernel_launch(void* const* d_in, const int* in_sizes, int n_in,
                              void* d_out, int out_size, void* d_ws, size_t ws_size,
                              hipStream_t stream) {
    const float* x   = (const float*)d_in[0];
    const int*   ei  = (const int*)d_in[1];
    const int*   nid = (const int*)d_in[2];
    const float* W   = (const float*)d_in[3];
    const float* Wid = (const float*)d_in[4];
    const float* att = (const float*)d_in[5];
    float* out = (float*)d_out;

    char* ws = (char*)d_ws;
    __hip_bfloat16* hb = (__hip_bfloat16*)(ws);            // 12,800,000 B
    float* ad    = (float*)(ws + 12800000);                //    400,000 B
    float* as    = (float*)(ws + 13200000);                //    400,000 B
    float* cnt   = (float*)(ws + 13600000);                //    400,000 B
    int*   cur   = (int*)  (ws + 14000000);                //    400,000 B
    int2*  binned = (int2*)(ws + 14400000);                // 14,413,824 B (NBUCK*CAP*8)
    int*   csr   = (int*)  (ws + 28900000);                //  7,206,912 B (NBUCK*CAP*4)
    unsigned short* WtG  = (unsigned short*)(ws + 36200000);  // 32,768 B
    unsigned short* WidG = (unsigned short*)(ws + 36232768);  // 32,768 B
    int*   bkcur = (int*)  (ws + 36265536);                //      1,564 B

    // init: cnt=0, bkcur[b]=b*CAP
    k_zero<<<393, 256, 0, stream>>>(cnt, bkcur);
    // prep: weight cvt+transpose | id multiplicity
    k_prep<<<168, 256, 0, stream>>>(W, Wid, WtG, WidG, nid, cnt);
    // mega: gemm (391 blocks) || edge binning (121 blocks) — all 512 co-resident
    k_mega<<<512, 512, 0, stream>>>(x, WtG, WidG, cnt, att, hb, ad, as, ei, bkcur, binned);
    // place: bucket-local hist/scan -> fixed-capacity csr + cur (512 thr)
    k_place<<<NBUCK, 512, 0, stream>>>(binned, bkcur, csr, cur);
    // gather: full-TLP v2
    k_gather<<<12500, 256, 0, stream>>>(cur, csr, (const unsigned*)hb, ad, as, out);
}

// Round 22
// 106.646 us; speedup vs baseline: 1.6525x; 1.6525x over previous
//
#include <hip/hip_runtime.h>
#include <hip/hip_bf16.h>

#define N_NODES 100000
#define E_EDGES 1600000
#define DIN 256
#define C_OUT 64
#define NID_CNT 10000
#define NEG 0.2f
#define NBUCK 391        // ceil(N_NODES/256) coarse buckets (dst >> 8)
#define CAP 4608         // fixed edges-capacity per bucket
#define GEMM_BLOCKS 391  // ceil(100000/256)
#define BIN_BLOCKS 121   // 391 + 121 = 512 = 2 blocks/CU * 256 CU (all co-resident)
#define BIN_EPB 13224    // ceil(E_EDGES/121)
#define BIN_ITERS 26     // ceil(13224/512)

typedef short bf16x8 __attribute__((ext_vector_type(8)));
typedef float f32x4  __attribute__((ext_vector_type(4)));

__device__ __forceinline__ float lrelu(float x) { return x > 0.f ? x : NEG * x; }
__device__ __forceinline__ unsigned short f2bs(float f) {
    __hip_bfloat16 b = __float2bfloat16(f);
    return *reinterpret_cast<unsigned short*>(&b);
}
__device__ __forceinline__ bf16x8 pack8(float4 a, float4 b) {
    bf16x8 r;
    r[0] = (short)f2bs(a.x); r[1] = (short)f2bs(a.y);
    r[2] = (short)f2bs(a.z); r[3] = (short)f2bs(a.w);
    r[4] = (short)f2bs(b.x); r[5] = (short)f2bs(b.y);
    r[6] = (short)f2bs(b.z); r[7] = (short)f2bs(b.w);
    return r;
}
__device__ __forceinline__ float2 unpk2(unsigned u) {
    return make_float2(__uint_as_float(u << 16), __uint_as_float(u & 0xffff0000u));
}

// ---------------- zero/init scratch ----------------
__global__ __launch_bounds__(256) void k_zero(float* __restrict__ cnt,
                                              int* __restrict__ bkcur) {
    const int t = blockIdx.x * 256 + threadIdx.x;
    if (t < N_NODES) cnt[t] = 0.f;
    if (t < NBUCK) bkcur[t] = t * CAP;   // fixed-capacity bucket bases
}

// ---------------- prep: W/Wid cvt+transpose | id multiplicity ----------------
__global__ __launch_bounds__(256) void k_prep(const float* __restrict__ W,
                                              const float* __restrict__ Wid,
                                              unsigned short* __restrict__ WtG,
                                              unsigned short* __restrict__ WidtG,
                                              const int* __restrict__ nid,
                                              float* __restrict__ cnt) {
    const int b = blockIdx.x;
    const int tid = threadIdx.x;
    if (b < 128) {                       // cvt: 32768 elements
        const int t = b * 256 + tid;
        const int mat = t >> 14;
        const int r = t & 16383;
        const int k = r >> 6, c = r & 63;
        if (mat == 0) WtG[c * DIN + k] = f2bs(W[(long)k * C_OUT + c]);
        else          WidtG[c * DIN + k] = f2bs(Wid[(long)k * C_OUT + c]);
    } else {                             // cnt: 10000 ids
        const int t = (b - 128) * 256 + tid;
        if (t < NID_CNT) atomicAdd(&cnt[nid[t]], 1.0f);
    }
}

// ---------------- mega kernel: gemm blocks (0..390) || bin blocks (391..511) ----------------
__global__ __launch_bounds__(512, 4) void k_mega(const float* __restrict__ x,
                                                 const unsigned short* __restrict__ WtG,
                                                 const unsigned short* __restrict__ WidtG,
                                                 const float* __restrict__ cnt,
                                                 const float* __restrict__ att,
                                                 __hip_bfloat16* __restrict__ hb,
                                                 float* __restrict__ ad,
                                                 float* __restrict__ as,
                                                 const int* __restrict__ ei,
                                                 int* __restrict__ bkcur,
                                                 int2* __restrict__ binned) {
    __shared__ __align__(16) char smem[66560];
    const int blk = blockIdx.x;
    const int tid = threadIdx.x;

    if (blk < GEMM_BLOCKS) {
        char* wlds = smem;                          // 64 KB: wt | wid (swizzled)
        float* cnt_lds = (float*)(smem + 65536);    // 1 KB
        const int w = tid >> 6, l = tid & 63;
        const int g = l >> 4, cl = l & 15;
        const int r0 = blk * 256;

        #pragma unroll
        for (int i = 0; i < 4; ++i) {
            int f = tid + i * 512;     // 2048 chunks of 16B
            int c = f >> 5, s = f & 31;
            int byte = c * 512 + ((s ^ (c & 7)) << 4);
            *(bf16x8*)(wlds + byte)         = *(const bf16x8*)(WtG + (long)c * DIN + s * 8);
            *(bf16x8*)(wlds + 32768 + byte) = *(const bf16x8*)(WidtG + (long)c * DIN + s * 8);
        }
        if (tid < 256) cnt_lds[tid] = (r0 + tid < N_NODES) ? cnt[r0 + tid] : 0.f;
        __syncthreads();

        f32x4 acc1[2][4] = {};
        f32x4 acc2[2][4] = {};

        const int row0 = r0 + w * 32 + cl;
        const float* xp0 = x + (long)min(row0, N_NODES - 1) * DIN + g * 8;
        const float* xp1 = x + (long)min(row0 + 16, N_NODES - 1) * DIN + g * 8;

        float4 xb[2][4];
        xb[0][0] = *(const float4*)(xp0);
        xb[0][1] = *(const float4*)(xp0 + 4);
        xb[0][2] = *(const float4*)(xp1);
        xb[0][3] = *(const float4*)(xp1 + 4);
        #pragma unroll
        for (int kt = 0; kt < 8; ++kt) {
            if (kt < 7) {
                const int nb = (kt + 1) & 1;
                xb[nb][0] = *(const float4*)(xp0 + (kt + 1) * 32);
                xb[nb][1] = *(const float4*)(xp0 + (kt + 1) * 32 + 4);
                xb[nb][2] = *(const float4*)(xp1 + (kt + 1) * 32);
                xb[nb][3] = *(const float4*)(xp1 + (kt + 1) * 32 + 4);
            }
            const int cb = kt & 1;
            bf16x8 a0 = pack8(xb[cb][0], xb[cb][1]);
            bf16x8 a1 = pack8(xb[cb][2], xb[cb][3]);
            #pragma unroll
            for (int ct = 0; ct < 4; ++ct) {
                int c = ct * 16 + cl;
                int byte = c * 512 + (((kt * 4 + g) ^ (c & 7)) << 4);
                bf16x8 bw = *(const bf16x8*)(wlds + byte);
                bf16x8 bi = *(const bf16x8*)(wlds + 32768 + byte);
                acc1[0][ct] = __builtin_amdgcn_mfma_f32_16x16x32_bf16(a0, bw, acc1[0][ct], 0, 0, 0);
                acc1[1][ct] = __builtin_amdgcn_mfma_f32_16x16x32_bf16(a1, bw, acc1[1][ct], 0, 0, 0);
                acc2[0][ct] = __builtin_amdgcn_mfma_f32_16x16x32_bf16(a0, bi, acc2[0][ct], 0, 0, 0);
                acc2[1][ct] = __builtin_amdgcn_mfma_f32_16x16x32_bf16(a1, bi, acc2[1][ct], 0, 0, 0);
            }
        }
        __syncthreads();

        float attv1[4], attv2[4];
        #pragma unroll
        for (int ct = 0; ct < 4; ++ct) {
            attv1[ct] = att[ct * 16 + cl];
            attv2[ct] = att[C_OUT + ct * 16 + cl];
        }
        unsigned short* hbt = (unsigned short*)wlds;  // tile stride 72 elems (144 B)
        #pragma unroll
        for (int rt = 0; rt < 2; ++rt) {
            #pragma unroll
            for (int reg = 0; reg < 4; ++reg) {
                const int rbl = w * 32 + rt * 16 + g * 4 + reg;
                const float cv = cnt_lds[rbl];
                float pd = 0.f, ps = 0.f;
                #pragma unroll
                for (int ct = 0; ct < 4; ++ct) {
                    float hv = acc1[rt][ct][reg] + cv * acc2[rt][ct][reg];
                    pd += hv * attv1[ct];
                    ps += hv * attv2[ct];
                    hbt[rbl * 72 + ct * 16 + cl] = f2bs(hv);
                }
                #pragma unroll
                for (int o = 1; o < 16; o <<= 1) {
                    pd += __shfl_xor(pd, o, 64);
                    ps += __shfl_xor(ps, o, 64);
                }
                if (cl == 0) {
                    int grow = r0 + rbl;
                    if (grow < N_NODES) { ad[grow] = pd; as[grow] = ps; }
                }
            }
        }
        __syncthreads();
        #pragma unroll
        for (int i = 0; i < 4; ++i) {
            int f = tid + i * 512;
            int row = f >> 3, s = f & 7;
            int grow = r0 + row;
            if (grow < N_NODES) {
                bf16x8 v = *(const bf16x8*)(wlds + row * 144 + s * 16);
                *(bf16x8*)((unsigned short*)hb + (long)grow * C_OUT + s * 8) = v;
            }
        }
    } else {
        // ---- bin role: register-staged two-phase scatter into bucket regions ----
        int* cnt_s = (int*)smem;         // NBUCK
        int* base  = cnt_s + NBUCK;      // NBUCK
        int* lcur  = base + NBUCK;       // NBUCK
        const int b2 = blk - GEMM_BLOCKS;
        const int e0 = b2 * BIN_EPB;
        const int e1 = min(e0 + BIN_EPB, E_EDGES);
        for (int i = tid; i < NBUCK; i += 512) cnt_s[i] = 0;
        __syncthreads();
        int se[BIN_ITERS], de[BIN_ITERS];
        #pragma unroll
        for (int j = 0; j < BIN_ITERS; ++j) {
            int e = e0 + j * 512 + tid;
            if (e < e1) {
                se[j] = ei[e];
                de[j] = ei[E_EDGES + e];
                atomicAdd(&cnt_s[de[j] >> 8], 1);
            } else de[j] = -1;
        }
        __syncthreads();
        for (int i = tid; i < NBUCK; i += 512) {
            base[i] = cnt_s[i] ? atomicAdd(&bkcur[i], cnt_s[i]) : 0;
            lcur[i] = 0;
        }
        __syncthreads();
        #pragma unroll
        for (int j = 0; j < BIN_ITERS; ++j) {
            if (de[j] >= 0) {
                int bb = de[j] >> 8;
                int r = atomicAdd(&lcur[bb], 1);
                binned[base[bb] + r] = make_int2(se[j], de[j]);
            }
        }
    }
}

// ---------------- place: one block per bucket -> fixed-capacity csr + cur ----------------
// 512 threads; scan section guarded to tid<256 with uniform barriers.
__global__ __launch_bounds__(512) void k_place(const int2* __restrict__ binned,
                                               const int* __restrict__ bkcur,
                                               int* __restrict__ csr,
                                               int* __restrict__ cur) {
    __shared__ int ncnt[256];
    __shared__ int tmp[256];
    __shared__ int ncur[256];
    const int tid = threadIdx.x;
    const int b = blockIdx.x;
    const int lo = b * CAP;
    const int n = bkcur[b] - lo;       // bucket edge count
    const int node0 = b << 8;
    if (tid < 256) ncnt[tid] = 0;
    __syncthreads();
    for (int e = tid; e < n; e += 512)
        atomicAdd(&ncnt[binned[lo + e].y - node0], 1);
    __syncthreads();
    const int v = (tid < 256) ? ncnt[tid] : 0;
    if (tid < 256) tmp[tid] = v;
    __syncthreads();
    for (int o = 1; o < 256; o <<= 1) {
        int t = (tid >= o && tid < 256) ? tmp[tid - o] : 0;
        __syncthreads();
        if (tid < 256) tmp[tid] += t;
        __syncthreads();
    }
    if (tid < 256) {
        const int incl = tmp[tid];
        if (node0 + tid < N_NODES) cur[node0 + tid] = lo + incl;  // global inclusive end
        ncur[tid] = incl - v;  // local exclusive start
    }
    __syncthreads();
    for (int e = tid; e < n; e += 512) {
        int2 p = binned[lo + e];
        int r = atomicAdd(&ncur[p.y - node0], 1);
        csr[lo + r] = p.x;
    }
}

// ---------------- gather: 2 nodes/wave (32-lane groups), 2 channels/lane (bf16x2) ----------------
__global__ __launch_bounds__(256) void k_gather(const int* __restrict__ cur,
                                                const int* __restrict__ csr,
                                                const unsigned* __restrict__ hb2,
                                                const float* __restrict__ ad,
                                                const float* __restrict__ as,
                                                float* __restrict__ out) {
    const int lane = threadIdx.x & 63;
    const int lg = lane & 31;                  // lane in group
    const int gb = lane & 32;                  // group broadcast base
    const int i = blockIdx.x * 8 + ((threadIdx.x >> 6) << 1) + (lane >> 5);
    if (i >= N_NODES) return;
    const int end   = cur[i];
    const int start = (i & 255) ? cur[i - 1] : (i >> 8) * CAP;  // fixed-cap bucket base
    const int deg   = end - start;
    const float adi = ad[i];
    const float asi = as[i];
    float2 acc;
    float den;
    if (deg <= 32) {
        int s = 0; float a = -1e30f;
        if (lg < deg) { s = csr[start + lg]; a = as[s]; }
        float mx = fmaxf(a, asi);
        #pragma unroll
        for (int o = 16; o > 0; o >>= 1) mx = fmaxf(mx, __shfl_xor(mx, o, 64));
        const float m = lrelu(adi + mx);
        float w = (lg < deg) ? __expf(lrelu(adi + a) - m) : 0.f;
        const float wself = __expf(lrelu(adi + asi) - m);
        float wsum = w;
        #pragma unroll
        for (int o = 16; o > 0; o >>= 1) wsum += __shfl_xor(wsum, o, 64);
        den = wself + wsum;
        float2 hv = unpk2(hb2[(long)i * 32 + lg]);
        acc = make_float2(wself * hv.x, wself * hv.y);
        int j = 0;
        for (; j + 4 <= deg; j += 4) {
            int   s0 = __shfl(s, gb + j, 64),     s1 = __shfl(s, gb + j + 1, 64),
                  s2 = __shfl(s, gb + j + 2, 64), s3 = __shfl(s, gb + j + 3, 64);
            float w0 = __shfl(w, gb + j, 64),     w1 = __shfl(w, gb + j + 1, 64),
                  w2 = __shfl(w, gb + j + 2, 64), w3 = __shfl(w, gb + j + 3, 64);
            float2 h0 = unpk2(hb2[(long)s0 * 32 + lg]);
            float2 h1 = unpk2(hb2[(long)s1 * 32 + lg]);
            float2 h2 = unpk2(hb2[(long)s2 * 32 + lg]);
            float2 h3 = unpk2(hb2[(long)s3 * 32 + lg]);
            acc.x += w0 * h0.x; acc.y += w0 * h0.y;
            acc.x += w1 * h1.x; acc.y += w1 * h1.y;
            acc.x += w2 * h2.x; acc.y += w2 * h2.y;
            acc.x += w3 * h3.x; acc.y += w3 * h3.y;
        }
        for (; j < deg; ++j) {
            int   sj = __shfl(s, gb + j, 64);
            float wj = __shfl(w, gb + j, 64);
            float2 hj = unpk2(hb2[(long)sj * 32 + lg]);
            acc.x += wj * hj.x; acc.y += wj * hj.y;
        }
    } else {  // rare: deg > 32
        float mx = asi;
        for (int b = 0; b < deg; b += 32) {
            int idx = b + lg;
            if (idx < deg) mx = fmaxf(mx, as[csr[start + idx]]);
        }
        #pragma unroll
        for (int o = 16; o > 0; o >>= 1) mx = fmaxf(mx, __shfl_xor(mx, o, 64));
        const float m = lrelu(adi + mx);
        const float wself = __expf(lrelu(adi + asi) - m);
        float2 hv = unpk2(hb2[(long)i * 32 + lg]);
        acc = make_float2(wself * hv.x, wself * hv.y);
        den = wself;
        for (int b = 0; b < deg; b += 32) {
            int idx = b + lg;
            int s = 0; float w = 0.f;
            if (idx < deg) {
                s = csr[start + idx];
                w = __expf(lrelu(adi + as[s]) - m);
            }
            const int cnt2 = min(32, deg - b);
            for (int j = 0; j < cnt2; ++j) {
                int   sj = __shfl(s, gb + j, 64);
                float wj = __shfl(w, gb + j, 64);
                float2 hj = unpk2(hb2[(long)sj * 32 + lg]);
                acc.x += wj * hj.x; acc.y += wj * hj.y;
            }
            float wsum = w;
            #pragma unroll
            for (int o = 16; o > 0; o >>= 1) wsum += __shfl_xor(wsum, o, 64);
            den += wsum;
        }
    }
    const float r = 1.f / (den + 1e-16f);
    *(float2*)(out + (long)i * C_OUT + lg * 2) = make_float2(acc.x * r, acc.y * r);
}

extern "C" void kernel_launch(void* const* d_in, const int* in_sizes, int n_in,
                              void* d_out, int out_size, void* d_ws, size_t ws_size,
                              hipStream_t stream) {
    const float* x   = (const float*)d_in[0];
    const int*   ei  = (const int*)d_in[1];
    const int*   nid = (const int*)d_in[2];
    const float* W   = (const float*)d_in[3];
    const float* Wid = (const float*)d_in[4];
    const float* att = (const float*)d_in[5];
    float* out = (float*)d_out;

    char* ws = (char*)d_ws;
    __hip_bfloat16* hb = (__hip_bfloat16*)(ws);            // 12,800,000 B
    float* ad    = (float*)(ws + 12800000);                //    400,000 B
    float* as    = (float*)(ws + 13200000);                //    400,000 B
    float* cnt   = (float*)(ws + 13600000);                //    400,000 B
    int*   cur   = (int*)  (ws + 14000000);                //    400,000 B
    int2*  binned = (int2*)(ws + 14400000);                // 14,413,824 B (NBUCK*CAP*8)
    int*   csr   = (int*)  (ws + 28900000);                //  7,206,912 B (NBUCK*CAP*4)
    unsigned short* WtG  = (unsigned short*)(ws + 36200000);  // 32,768 B
    unsigned short* WidG = (unsigned short*)(ws + 36232768);  // 32,768 B
    int*   bkcur = (int*)  (ws + 36265536);                //      1,564 B

    // init: cnt=0, bkcur[b]=b*CAP
    k_zero<<<393, 256, 0, stream>>>(cnt, bkcur);
    // prep: weight cvt+transpose | id multiplicity
    k_prep<<<168, 256, 0, stream>>>(W, Wid, WtG, WidG, nid, cnt);
    // mega: gemm (391 blocks) || edge binning (121 blocks) — all 512 co-resident
    k_mega<<<512, 512, 0, stream>>>(x, WtG, WidG, cnt, att, hb, ad, as, ei, bkcur, binned);
    // place: bucket-local hist/scan -> fixed-capacity csr + cur (512 thr)
    k_place<<<NBUCK, 512, 0, stream>>>(binned, bkcur, csr, cur);
    // gather: full-TLP v2
    k_gather<<<12500, 256, 0, stream>>>(cur, csr, (const unsigned*)hb, ad, as, out);
}